// Round 12
// baseline (116.243 us; speedup 1.0000x reference)
//
#include <hip/hip_runtime.h>

#define NPTS 1024
#define NN (NPTS * NPTS)
#define NEDGE 32768
#define INDIM 128
#define W_ELL 128

// ---------------- 1. init: zero counters, compute p ----------------
// grid 256 x 256: wave per node for p; t<4 zeroes cnt/dc/dd entries.
__global__ void init_kernel(const float* __restrict__ feat,
                            const float* __restrict__ w,
                            const float* __restrict__ b,
                            float* __restrict__ p,
                            int* __restrict__ cnt,
                            float* __restrict__ dc,
                            float* __restrict__ dd) {
    int t = threadIdx.x;
    if (t < 4) {
        int i = blockIdx.x * 4 + t;
        cnt[i] = 0;
        dc[i] = 0.f;
        dd[i] = 0.f;
    }
    int wid = t >> 6, lane = t & 63;
    int node = blockIdx.x * 4 + wid;
    const float* f = feat + node * INDIM;
    float s = f[lane] * w[lane] + f[lane + 64] * w[lane + 64];
#pragma unroll
    for (int off = 32; off; off >>= 1) s += __shfl_down(s, off);
    if (lane == 0) p[node] = s + b[0];
}

// ---------------- 2. edge pass: ELL push + degrees ----------------
__global__ void edge_kernel(const int* __restrict__ eu, const int* __restrict__ ev,
                            const float* __restrict__ p,
                            int* __restrict__ ellc, float* __restrict__ ellv,
                            int* __restrict__ cnt,
                            float* __restrict__ dc, float* __restrict__ dd) {
    int i = blockIdx.x * blockDim.x + threadIdx.x;
    if (i >= NEDGE) return;
    int u = eu[i], v = ev[i];
    float val = p[u] - p[v];
    if (val > 0.f) {
        float w = 1.f + val;
        int pu = atomicAdd(&cnt[u], 1);
        if (pu <= W_ELL - 2) { ellc[u * W_ELL + pu] = v; ellv[u * W_ELL + pu] = w; }
        int pv = atomicAdd(&cnt[v], 1);
        if (pv <= W_ELL - 2) { ellc[v * W_ELL + pv] = u; ellv[v * W_ELL + pv] = w; }
        atomicAdd(&dd[u], w);
        atomicAdd(&dd[v], w);
    } else {
        atomicAdd(&dc[u], 1.f);
        atomicAdd(&dc[v], 1.f);
        atomicAdd(&dd[u], 1.f);
        atomicAdd(&dd[v], 1.f);
    }
}

// ---------------- 3. rowbuild: normalize ELL, diag, T0/T1 rows ----------------
// block per row (1024 blocks x 256 thr).
__global__ void rowbuild_kernel(int* __restrict__ ellc, float* __restrict__ ellv,
                                int* __restrict__ cnt,
                                const float* __restrict__ dc, const float* __restrict__ dd,
                                float* __restrict__ out) {
    int i = blockIdx.x, t = threadIdx.x;
    __shared__ float row[NPTS];
    row[t] = 0.f; row[t + 256] = 0.f; row[t + 512] = 0.f; row[t + 768] = 0.f;
    __syncthreads();
    float di = rsqrtf(dd[i] + 1.f);
    int n = cnt[i];
    if (n > W_ELL - 1) n = W_ELL - 1;  // safety clamp (never hit statistically)
    for (int e = t; e < n; e += 256) {
        int c = ellc[i * W_ELL + e];
        float m = -(di * ellv[i * W_ELL + e] * rsqrtf(dd[c] + 1.f));
        ellv[i * W_ELL + e] = m;  // in-place normalized M value
        atomicAdd(&row[c], m);
    }
    if (t == 0) {
        float mdiag = -(di * di * (dc[i] + 1.f));
        ellc[i * W_ELL + n] = i;
        ellv[i * W_ELL + n] = mdiag;
        int np = (n + 1 + 7) & ~7;  // pad to multiple of 8 with zero entries
        for (int k = n + 1; k < np; ++k) { ellc[i * W_ELL + k] = 0; ellv[i * W_ELL + k] = 0.f; }
        cnt[i] = np;
        atomicAdd(&row[i], mdiag);
    }
    __syncthreads();
    // T0 row (identity) and T1 row (M dense)
    float4* T0r = (float4*)(out + (size_t)i * NPTS);
    float4* T1r = (float4*)(out + (size_t)NN + (size_t)i * NPTS);
    float4 z = make_float4(0.f, 0.f, 0.f, 0.f);
    if ((i >> 2) == t) ((float*)&z)[i & 3] = 1.f;
    T0r[t] = z;
    T1r[t] = *(float4*)&row[t * 4];
}

// ---------------- 4-6. SpMM: Out = M(sparse) * In(dense) ----------------
// block per output row. ELL row staged in LDS; all lanes broadcast-read each
// entry and gather In row col*4KB with coalesced float4.
// phase 1: Raw=S, Tout=T2=2S-I          (+ hidden imag zero if zimag)
// phase 2: Raw=R, Tout=T3=4R-3*Aux(T1)
// phase 3:        Tout=T4=8Q-8*Aux(S)+I
__global__ void spmm_kernel(const int* __restrict__ ellc, const float* __restrict__ ellv,
                            const int* __restrict__ cnt,
                            const float* __restrict__ In,
                            float* __restrict__ Raw, float* __restrict__ Tout,
                            const float* __restrict__ Aux,
                            float* __restrict__ imagbase,
                            int phase, int zimag) {
    int i = blockIdx.x, t = threadIdx.x;
    if (phase == 1 && zimag) {
        float4* z = (float4*)imagbase + (size_t)i * 1280 + t;
#pragma unroll
        for (int k = 0; k < 5; ++k) z[k * 256] = make_float4(0.f, 0.f, 0.f, 0.f);
    }
    __shared__ int sc[W_ELL];
    __shared__ float sv[W_ELL];
    int n = cnt[i];
    if (t < n) { sc[t] = ellc[i * W_ELL + t]; sv[t] = ellv[i * W_ELL + t]; }
    __syncthreads();

    const float4* In4 = (const float4*)In;
    float4 acc = make_float4(0.f, 0.f, 0.f, 0.f);
    for (int e = 0; e < n; e += 8) {
#pragma unroll
        for (int k = 0; k < 8; ++k) {
            float wv = sv[e + k];
            float4 x = In4[(size_t)sc[e + k] * 256 + t];
            acc.x += wv * x.x;
            acc.y += wv * x.y;
            acc.z += wv * x.z;
            acc.w += wv * x.w;
        }
    }

    size_t idx = (size_t)i * 256 + t;
    int dt = i >> 2, dcc = i & 3;
    if (phase == 1) {
        ((float4*)Raw)[idx] = acc;
        float4 o = make_float4(2.f * acc.x, 2.f * acc.y, 2.f * acc.z, 2.f * acc.w);
        if (t == dt) ((float*)&o)[dcc] -= 1.f;
        ((float4*)Tout)[idx] = o;
    } else if (phase == 2) {
        ((float4*)Raw)[idx] = acc;
        float4 a = ((const float4*)Aux)[idx];
        float4 o = make_float4(4.f * acc.x - 3.f * a.x, 4.f * acc.y - 3.f * a.y,
                               4.f * acc.z - 3.f * a.z, 4.f * acc.w - 3.f * a.w);
        ((float4*)Tout)[idx] = o;
    } else {
        float4 a = ((const float4*)Aux)[idx];
        float4 o = make_float4(8.f * acc.x - 8.f * a.x, 8.f * acc.y - 8.f * a.y,
                               8.f * acc.z - 8.f * a.z, 8.f * acc.w - 8.f * a.w);
        if (t == dt) ((float*)&o)[dcc] += 1.f;
        ((float4*)Tout)[idx] = o;
    }
}

__global__ void zero_kernel(float4* __restrict__ p, int n4) {
    int i = blockIdx.x * blockDim.x + threadIdx.x;
    if (i < n4) p[i] = make_float4(0.f, 0.f, 0.f, 0.f);
}

// ---------------- launch ----------------

extern "C" void kernel_launch(void* const* d_in, const int* in_sizes, int n_in,
                              void* d_out, int out_size, void* d_ws, size_t ws_size,
                              hipStream_t stream) {
    const float* feat = (const float*)d_in[0];
    const int* edges = (const int*)d_in[1];
    const float* w_e1 = (const float*)d_in[2];
    const float* b_e1 = (const float*)d_in[3];
    float* out = (float*)d_out;

    // scratch: S(4MB) R(4MB) ellc(512KB) ellv(512KB) cnt/dc/dd/p (4KB each)
    const size_t need = (size_t)NN * 8 + (size_t)NPTS * W_ELL * 8 + NPTS * 16 + 256;
    float* S;
    float* R;
    int* ellc;
    float* ellv;
    int* cnt;
    float* dc;
    float* dd;
    float* p;
    int use_ws = (ws_size >= need);
    if (use_ws) {
        char* w = (char*)d_ws;
        S = (float*)w;                      w += (size_t)NN * 4;
        R = (float*)w;                      w += (size_t)NN * 4;
        ellc = (int*)w;                     w += (size_t)NPTS * W_ELL * 4;
        ellv = (float*)w;                   w += (size_t)NPTS * W_ELL * 4;
        cnt = (int*)w;                      w += NPTS * 4;
        dc = (float*)w;                     w += NPTS * 4;
        dd = (float*)w;                     w += NPTS * 4;
        p = (float*)w;
    } else {
        S = out + (size_t)5 * NN;
        R = out + (size_t)6 * NN;
        ellc = (int*)(out + (size_t)7 * NN);
        ellv = (float*)(out + (size_t)7 * NN) + NPTS * W_ELL;
        cnt = (int*)(out + (size_t)7 * NN) + 2 * NPTS * W_ELL;
        dc = (float*)cnt + NPTS;
        dd = dc + NPTS;
        p = dd + NPTS;
    }

    init_kernel<<<256, 256, 0, stream>>>(feat, w_e1, b_e1, p, cnt, dc, dd);
    edge_kernel<<<NEDGE / 256, 256, 0, stream>>>(edges, edges + NEDGE, p,
                                                 ellc, ellv, cnt, dc, dd);
    rowbuild_kernel<<<NPTS, 256, 0, stream>>>(ellc, ellv, cnt, dc, dd, out);

    float* T1 = out + (size_t)NN;
    float* T2 = out + (size_t)2 * NN;
    float* T3 = out + (size_t)3 * NN;
    float* T4 = out + (size_t)4 * NN;
    float* imagbase = out + (size_t)5 * NN;

    // S = M*T1 -> T2;  R = M*S -> T3;  Q = M*R -> T4
    spmm_kernel<<<NPTS, 256, 0, stream>>>(ellc, ellv, cnt, T1, S, T2, nullptr,
                                          imagbase, 1, use_ws);
    spmm_kernel<<<NPTS, 256, 0, stream>>>(ellc, ellv, cnt, S, R, T3, T1,
                                          imagbase, 2, 0);
    spmm_kernel<<<NPTS, 256, 0, stream>>>(ellc, ellv, cnt, R, nullptr, T4, S,
                                          imagbase, 3, 0);

    if (!use_ws) {
        zero_kernel<<<(5 * NN / 4 + 255) / 256, 256, 0, stream>>>(
            (float4*)(out + (size_t)5 * NN), 5 * NN / 4);
    }
}

// Round 13
// 51.040 us; speedup vs baseline: 2.2775x; 2.2775x over previous
//
#include <hip/hip_runtime.h>

#define NPTS 1024
#define NN (NPTS * NPTS)
#define NEDGE 32768
#define INDIM 128
#define PAD 72

typedef __attribute__((ext_vector_type(8))) short bf16x8;
typedef __attribute__((ext_vector_type(4))) float f32x4;

__device__ inline ushort f2bf(float x) {
    union { float f; unsigned u; } v; v.f = x;
    unsigned r = (v.u + 0x7FFF + ((v.u >> 16) & 1)) >> 16;
    return (ushort)r;
}

#define MFMA(a, b, c) __builtin_amdgcn_mfma_f32_16x16x32_bf16(a, b, c, 0, 0, 0)

// ---------------- front-end kernels (R5-proven; A-zero moved to memset) ----

// grid 256 x 256: one wave per node
__global__ void p_kernel(const float* __restrict__ feat,
                         const float* __restrict__ w,
                         const float* __restrict__ b,
                         float* __restrict__ p) {
    int t = threadIdx.x;
    int wid = t >> 6, lane = t & 63;
    int node = blockIdx.x * 4 + wid;
    const float* f = feat + node * INDIM;
    float s = f[lane] * w[lane] + f[lane + 64] * w[lane + 64];
#pragma unroll
    for (int off = 32; off; off >>= 1) s += __shfl_down(s, off);
    if (lane == 0) p[node] = s + b[0];
}

__global__ void build_A_kernel(const int* __restrict__ eu, const int* __restrict__ ev,
                               const float* __restrict__ p, float* __restrict__ A) {
    int i = blockIdx.x * blockDim.x + threadIdx.x;
    if (i >= NEDGE) return;
    int u = eu[i], v = ev[i];
    float val = p[u] - p[v];
    if (val > 0.f) {
        float w = 1.f + val;
        atomicAdd(&A[u * NPTS + v], w);
        atomicAdd(&A[v * NPTS + u], w);
    } else {
        atomicAdd(&A[u * NPTS + u], 1.f);
        atomicAdd(&A[v * NPTS + v], 1.f);
    }
}

// wave per row: dinv[row] = rsqrt(1 + sum_j A[row][j])
__global__ void row_deg_kernel(const float* __restrict__ A, float* __restrict__ dinv) {
    int wid = threadIdx.x >> 6, lane = threadIdx.x & 63;
    int row = blockIdx.x * 4 + wid;
    const float4* r4 = (const float4*)(A + (size_t)row * NPTS);
    float s = 0.f;
#pragma unroll
    for (int c = 0; c < 4; ++c) {
        float4 v = r4[c * 64 + lane];
        s += v.x + v.y + v.z + v.w;
    }
#pragma unroll
    for (int off = 32; off; off >>= 1) s += __shfl_down(s, off);
    if (lane == 0) dinv[row] = rsqrtf(s + 1.f);
}

__global__ void normalize_kernel(const float* __restrict__ A, const float* __restrict__ dinv,
                                 float* __restrict__ out, ushort* __restrict__ Mbf) {
    int idx4 = blockIdx.x * blockDim.x + threadIdx.x;
    int i = idx4 >> 8;
    int j = (idx4 & 255) * 4;
    size_t idx = (size_t)idx4 * 4;
    float di = dinv[i];
    float4 a = *(const float4*)(A + idx);
    float4 dj = *(const float4*)(dinv + j);
    float4 t0 = make_float4(0.f, 0.f, 0.f, 0.f);
    if (i == j) t0.x = 1.f;
    else if (i == j + 1) t0.y = 1.f;
    else if (i == j + 2) t0.z = 1.f;
    else if (i == j + 3) t0.w = 1.f;
    a.x += (i == j);
    a.y += (i == j + 1);
    a.z += (i == j + 2);
    a.w += (i == j + 3);
    float4 m;
    m.x = -(di * a.x * dj.x);
    m.y = -(di * a.y * dj.y);
    m.z = -(di * a.z * dj.z);
    m.w = -(di * a.w * dj.w);
    *(float4*)(out + idx) = t0;
    *(float4*)(out + NN + idx) = m;
    ushort mb[4] = {f2bf(m.x), f2bf(m.y), f2bf(m.z), f2bf(m.w)};
    *(uint2*)(Mbf + idx) = *(uint2*)mb;
}

// ---------------- MFMA GEMMs (R5-proven split-K-2) + XCD swizzle ----------
// 64x64 tile, 512 thr = 8 waves, BK=128 as 2 sub-buffers; group h=wid>>2
// consumes sub-buffer h; wave w4 owns 32x32 (2x2 of 16x16x32). LDS reduction
// combines the two K-halves. Block IDs remapped so each XCD gets 32
// consecutive tiles (2 full tile-rows) -> A-row-band L2 locality per XCD.

__device__ inline int xcd_swizzle(int lin) {
    // nwg=256, 8 XCDs, q=32: bijective chunked remap (m204)
    return (lin & 7) * 32 + (lin >> 3);
}

// phase 0: S = M*M -> T2 = 2S - I, Sbf = bf16(S)
__global__ __launch_bounds__(512) void gemm_S_kernel(const ushort* __restrict__ Mbf,
                                                     ushort* __restrict__ Sbf,
                                                     float* __restrict__ out) {
    __shared__ __align__(16) ushort smem[4 * 64 * PAD];  // 36.9 KB
    ushort(*sA)[64][PAD] = (ushort(*)[64][PAD])smem;
    ushort(*sB)[64][PAD] = (ushort(*)[64][PAD])(smem + 2 * 64 * PAD);
    float* red = (float*)smem;  // 16 KB reduction region (within smem)

    int tid = threadIdx.x;
    int swz = xcd_swizzle(blockIdx.y * 16 + blockIdx.x);
    int brow = (swz >> 4) * 64, bcol = (swz & 15) * 64;
    int r = tid >> 3, j0 = (tid & 7) * 8;
    int wid = tid >> 6, lane = tid & 63;
    int h = wid >> 2, w4 = wid & 3;
    int wr = (w4 & 1) * 32, wc = (w4 >> 1) * 32;
    int fr = lane & 15, g = lane >> 4;

    const ushort* Arow = Mbf + (size_t)(brow + r) * NPTS;
    const ushort* Brow = Mbf + (size_t)(bcol + r) * NPTS;

    f32x4 acc[2][2] = {};
    float4 pa0 = *(const float4*)(Arow + j0);
    float4 pa1 = *(const float4*)(Arow + 64 + j0);
    float4 pb0 = *(const float4*)(Brow + j0);
    float4 pb1 = *(const float4*)(Brow + 64 + j0);

    for (int it = 0; it < 8; ++it) {
        __syncthreads();
        *(float4*)&sA[0][r][j0] = pa0;
        *(float4*)&sA[1][r][j0] = pa1;
        *(float4*)&sB[0][r][j0] = pb0;
        *(float4*)&sB[1][r][j0] = pb1;
        __syncthreads();
        if (it < 7) {
            int k0 = (it + 1) * 128;
            pa0 = *(const float4*)(Arow + k0 + j0);
            pa1 = *(const float4*)(Arow + k0 + 64 + j0);
            pb0 = *(const float4*)(Brow + k0 + j0);
            pb1 = *(const float4*)(Brow + k0 + 64 + j0);
        }
#pragma unroll
        for (int kc = 0; kc < 2; ++kc) {
            int kk = kc * 32 + g * 8;
            bf16x8 a0 = *(const bf16x8*)&sA[h][wr + fr][kk];
            bf16x8 a1 = *(const bf16x8*)&sA[h][wr + 16 + fr][kk];
            bf16x8 b0 = *(const bf16x8*)&sB[h][wc + fr][kk];
            bf16x8 b1 = *(const bf16x8*)&sB[h][wc + 16 + fr][kk];
            acc[0][0] = MFMA(a0, b0, acc[0][0]);
            acc[0][1] = MFMA(a0, b1, acc[0][1]);
            acc[1][0] = MFMA(a1, b0, acc[1][0]);
            acc[1][1] = MFMA(a1, b1, acc[1][1]);
        }
    }

    __syncthreads();
    if (h == 1) {
#pragma unroll
        for (int q = 0; q < 4; ++q)
            *(f32x4*)&red[q * 1024 + (w4 * 64 + lane) * 4] = acc[q >> 1][q & 1];
    }
    __syncthreads();
    if (h == 0) {
        float* T2 = out + (size_t)2 * NN;
#pragma unroll
        for (int mi = 0; mi < 2; ++mi) {
#pragma unroll
            for (int ni = 0; ni < 2; ++ni) {
                f32x4 o = *(f32x4*)&red[(mi * 2 + ni) * 1024 + (w4 * 64 + lane) * 4];
#pragma unroll
                for (int q = 0; q < 4; ++q) {
                    int row = brow + wr + mi * 16 + g * 4 + q;
                    int col = bcol + wc + ni * 16 + fr;
                    size_t idx = (size_t)row * NPTS + col;
                    float s = acc[mi][ni][q] + o[q];
                    T2[idx] = 2.f * s - (row == col ? 1.f : 0.f);
                    Sbf[idx] = f2bf(s);
                }
            }
        }
    }
}

// phase 1 (fused): P = S*S -> T4 = 8P - 4*T2 - 3I;  R = M*S -> T3 = 4R - 3*T1
__global__ __launch_bounds__(512) void gemm_T34_kernel(const ushort* __restrict__ Mbf,
                                                       const ushort* __restrict__ Sbf,
                                                       float* __restrict__ out,
                                                       int zimag) {
    // hidden zeroing of the imag half (20.9 MB over 256 blocks)
    if (zimag) {
        int bid = blockIdx.y * 16 + blockIdx.x;
        float4* z = (float4*)(out + (size_t)5 * NN) + (size_t)bid * 5120 + threadIdx.x;
#pragma unroll
        for (int i = 0; i < 10; ++i) z[i * 512] = make_float4(0.f, 0.f, 0.f, 0.f);
    }

    __shared__ __align__(16) ushort smem[6 * 64 * PAD];  // 55.3 KB
    ushort(*sAS)[64][PAD] = (ushort(*)[64][PAD])smem;
    ushort(*sAM)[64][PAD] = (ushort(*)[64][PAD])(smem + 2 * 64 * PAD);
    ushort(*sB)[64][PAD] = (ushort(*)[64][PAD])(smem + 4 * 64 * PAD);
    float* red = (float*)smem;  // 32 KB reduction region (within smem)

    int tid = threadIdx.x;
    int swz = xcd_swizzle(blockIdx.y * 16 + blockIdx.x);
    int brow = (swz >> 4) * 64, bcol = (swz & 15) * 64;
    int r = tid >> 3, j0 = (tid & 7) * 8;
    int wid = tid >> 6, lane = tid & 63;
    int h = wid >> 2, w4 = wid & 3;
    int wr = (w4 & 1) * 32, wc = (w4 >> 1) * 32;
    int fr = lane & 15, g = lane >> 4;

    const ushort* ASrow = Sbf + (size_t)(brow + r) * NPTS;
    const ushort* AMrow = Mbf + (size_t)(brow + r) * NPTS;
    const ushort* Brow = Sbf + (size_t)(bcol + r) * NPTS;

    f32x4 accP[2][2] = {};
    f32x4 accR[2][2] = {};
    float4 ps0 = *(const float4*)(ASrow + j0);
    float4 ps1 = *(const float4*)(ASrow + 64 + j0);
    float4 pm0 = *(const float4*)(AMrow + j0);
    float4 pm1 = *(const float4*)(AMrow + 64 + j0);
    float4 pb0 = *(const float4*)(Brow + j0);
    float4 pb1 = *(const float4*)(Brow + 64 + j0);

    for (int it = 0; it < 8; ++it) {
        __syncthreads();
        *(float4*)&sAS[0][r][j0] = ps0;
        *(float4*)&sAS[1][r][j0] = ps1;
        *(float4*)&sAM[0][r][j0] = pm0;
        *(float4*)&sAM[1][r][j0] = pm1;
        *(float4*)&sB[0][r][j0] = pb0;
        *(float4*)&sB[1][r][j0] = pb1;
        __syncthreads();
        if (it < 7) {
            int k0 = (it + 1) * 128;
            ps0 = *(const float4*)(ASrow + k0 + j0);
            ps1 = *(const float4*)(ASrow + k0 + 64 + j0);
            pm0 = *(const float4*)(AMrow + k0 + j0);
            pm1 = *(const float4*)(AMrow + k0 + 64 + j0);
            pb0 = *(const float4*)(Brow + k0 + j0);
            pb1 = *(const float4*)(Brow + k0 + 64 + j0);
        }
#pragma unroll
        for (int kc = 0; kc < 2; ++kc) {
            int kk = kc * 32 + g * 8;
            bf16x8 b0 = *(const bf16x8*)&sB[h][wc + fr][kk];
            bf16x8 b1 = *(const bf16x8*)&sB[h][wc + 16 + fr][kk];
            bf16x8 s0 = *(const bf16x8*)&sAS[h][wr + fr][kk];
            bf16x8 s1 = *(const bf16x8*)&sAS[h][wr + 16 + fr][kk];
            accP[0][0] = MFMA(s0, b0, accP[0][0]);
            accP[0][1] = MFMA(s0, b1, accP[0][1]);
            accP[1][0] = MFMA(s1, b0, accP[1][0]);
            accP[1][1] = MFMA(s1, b1, accP[1][1]);
            bf16x8 m0 = *(const bf16x8*)&sAM[h][wr + fr][kk];
            bf16x8 m1 = *(const bf16x8*)&sAM[h][wr + 16 + fr][kk];
            accR[0][0] = MFMA(m0, b0, accR[0][0]);
            accR[0][1] = MFMA(m0, b1, accR[0][1]);
            accR[1][0] = MFMA(m1, b0, accR[1][0]);
            accR[1][1] = MFMA(m1, b1, accR[1][1]);
        }
    }

    __syncthreads();
    if (h == 1) {
#pragma unroll
        for (int q = 0; q < 4; ++q) {
            *(f32x4*)&red[q * 1024 + (w4 * 64 + lane) * 4] = accP[q >> 1][q & 1];
            *(f32x4*)&red[4096 + q * 1024 + (w4 * 64 + lane) * 4] = accR[q >> 1][q & 1];
        }
    }
    __syncthreads();
    if (h == 0) {
        float* T1 = out + (size_t)NN;
        float* T2 = out + (size_t)2 * NN;
        float* T3 = out + (size_t)3 * NN;
        float* T4 = out + (size_t)4 * NN;
#pragma unroll
        for (int mi = 0; mi < 2; ++mi) {
#pragma unroll
            for (int ni = 0; ni < 2; ++ni) {
                f32x4 oP = *(f32x4*)&red[(mi * 2 + ni) * 1024 + (w4 * 64 + lane) * 4];
                f32x4 oR = *(f32x4*)&red[4096 + (mi * 2 + ni) * 1024 + (w4 * 64 + lane) * 4];
#pragma unroll
                for (int q = 0; q < 4; ++q) {
                    int row = brow + wr + mi * 16 + g * 4 + q;
                    int col = bcol + wc + ni * 16 + fr;
                    size_t idx = (size_t)row * NPTS + col;
                    float sp = accP[mi][ni][q] + oP[q];
                    float sr = accR[mi][ni][q] + oR[q];
                    T4[idx] = 8.f * sp - 4.f * T2[idx] - (row == col ? 3.f : 0.f);
                    T3[idx] = 4.f * sr - 3.f * T1[idx];
                }
            }
        }
    }
}

__global__ void zero_kernel(float4* __restrict__ p, int n4) {
    int i = blockIdx.x * blockDim.x + threadIdx.x;
    if (i < n4) p[i] = make_float4(0.f, 0.f, 0.f, 0.f);
}

// ---------------- launch ----------------

extern "C" void kernel_launch(void* const* d_in, const int* in_sizes, int n_in,
                              void* d_out, int out_size, void* d_ws, size_t ws_size,
                              hipStream_t stream) {
    const float* feat = (const float*)d_in[0];
    const int* edges = (const int*)d_in[1];
    const float* w_e1 = (const float*)d_in[2];
    const float* b_e1 = (const float*)d_in[3];
    float* out = (float*)d_out;

    const size_t need = (size_t)NN * 4 + (size_t)NN * 2 + (size_t)NN * 2 + NPTS * 8 + 256;
    float* A;
    ushort* Mbf;
    ushort* Sbf;
    float* p;
    float* dinv;
    int use_ws = (ws_size >= need);
    if (use_ws) {
        char* w = (char*)d_ws;
        A = (float*)w;        w += (size_t)NN * 4;
        Mbf = (ushort*)w;     w += (size_t)NN * 2;
        Sbf = (ushort*)w;     w += (size_t)NN * 2;
        p = (float*)w;        w += NPTS * 4;
        dinv = (float*)w;
    } else {
        A = out + (size_t)5 * NN;
        Mbf = (ushort*)(out + (size_t)6 * NN);
        Sbf = Mbf + NN;
        p = out + (size_t)7 * NN;
        dinv = p + NPTS;
    }

    hipMemsetAsync(A, 0, (size_t)NN * 4, stream);  // fill engine, ~0.7us
    p_kernel<<<256, 256, 0, stream>>>(feat, w_e1, b_e1, p);
    build_A_kernel<<<(NEDGE + 255) / 256, 256, 0, stream>>>(edges, edges + NEDGE, p, A);
    row_deg_kernel<<<256, 256, 0, stream>>>(A, dinv);
    normalize_kernel<<<NN / 4 / 256, 256, 0, stream>>>(A, dinv, out, Mbf);

    dim3 grid(16, 16);
    gemm_S_kernel<<<grid, 512, 0, stream>>>(Mbf, Sbf, out);
    gemm_T34_kernel<<<grid, 512, 0, stream>>>(Mbf, Sbf, out, use_ws);

    if (!use_ws) {
        zero_kernel<<<(5 * NN / 4 + 255) / 256, 256, 0, stream>>>(
            (float4*)(out + (size_t)5 * NN), 5 * NN / 4);
    }
}